// Round 1
// baseline (219.098 us; speedup 1.0000x reference)
//
#include <hip/hip_runtime.h>

// LSTM: B=4096, T=256, I=8, H=32, O=1, fp32 in/out, bf16 MFMA compute.
// Decomposition: 256 tiles of 16 batch rows; 1 block (4 waves) per tile.
//   wave w owns gate w (PyTorch order i,f,g,o = rows 32w..32w+31 of W):
//     z[16x32] = x_t @ W_ih^T + (b_ih+b_hh) + h @ W_hh^T  via 4 MFMAs/step
//   activated gates -> LDS -> c/h update split 4-ways by hidden index j.
// Weights stay in B-fragment registers for all 256 steps (scaled by log2e
// so sigmoid/tanh need only v_exp_f32 + v_rcp_f32).

#define T_LEN 256
#define LOG2E 1.4426950408889634f

typedef __attribute__((ext_vector_type(8))) short bf16x8;
typedef __attribute__((ext_vector_type(4))) float f32x4;

static __device__ inline short f2bf(float f) {
    union { float f; unsigned u; } v; v.f = f;
    unsigned u = v.u;
    unsigned r = (u + 0x7FFFu + ((u >> 16) & 1u)) >> 16;  // RNE
    return (short)r;
}
static __device__ inline float bf2f(short s) {
    union { unsigned u; float f; } v;
    v.u = ((unsigned)(unsigned short)s) << 16;
    return v.f;
}

__global__ __launch_bounds__(256) void lstm_kernel(
    const float* __restrict__ x, const float* __restrict__ W_ih,
    const float* __restrict__ W_hh, const float* __restrict__ b_ih,
    const float* __restrict__ b_hh, const float* __restrict__ W_out,
    const float* __restrict__ b_out, float* __restrict__ out)
{
    // gate_lds[gate][j(0..31)][m stride 20 dwords]  (20-dword rows: 16B-aligned
    // float4 stores, <=2-way bank aliasing which is free)
    __shared__ __attribute__((aligned(16))) float gate_lds[4 * 32 * 20];
    // h_lds[m(0..15)][k(0..31)] bf16, row stride 40 shorts = 80 B (16B aligned)
    __shared__ __attribute__((aligned(16))) short h_lds[16 * 40];

    const int tid  = threadIdx.x;
    const int w    = tid >> 6;        // wave 0..3 == gate i,f,g,o
    const int lane = tid & 63;
    const int L15  = lane & 15;
    const int q    = lane >> 4;       // quad 0..3
    const int row0 = blockIdx.x * 16; // 16 batch rows per tile

    // ---- one-time: weight fragments (B-operand layout: n=lane&15, k=q*8+j) ----
    bf16x8 whh[2], wih[2];
    f32x4  bias4[2];
#pragma unroll
    for (int a = 0; a < 2; ++a) {
        const int n = 32 * w + 16 * a + L15;      // global gate-row 0..127
        const float* src = W_hh + n * 32 + q * 8; // W_hh[n][k], contiguous in k
        bf16x8 fr;
#pragma unroll
        for (int j = 0; j < 8; ++j) fr[j] = f2bf(src[j] * LOG2E);
        whh[a] = fr;
        bf16x8 gr = (bf16x8){0,0,0,0,0,0,0,0};
        if (q == 0) {                              // only k=0..7 exist (I=8)
            const float* s2 = W_ih + n * 8;
#pragma unroll
            for (int j = 0; j < 8; ++j) gr[j] = f2bf(s2[j] * LOG2E);
        }
        wih[a] = gr;
        const float bt = (b_ih[n] + b_hh[n]) * LOG2E;
        bias4[a] = (f32x4){bt, bt, bt, bt};
    }

    // zero initial hidden state
    for (int i = tid; i < 16 * 40; i += 256) h_lds[i] = 0;

    // c-state ownership for the update phase: j = 8w + (lane>>3), m = (lane&7)*2 + e
    const int uj = 8 * w + (lane >> 3);
    const int um = (lane & 7) * 2;
    float c0 = 0.f, c1 = 0.f;

    // x prefetch (t=0): lanes q==0 hold A-frag rows (m=L15), k=0..7
    const float4* xv = (const float4*)x;
    const size_t xbase = (size_t)(row0 + L15) * 512; // (row*T*I)/4
    float4 xr0 = {0,0,0,0}, xr1 = {0,0,0,0};
    if (q == 0) { xr0 = xv[xbase]; xr1 = xv[xbase + 1]; }

    __syncthreads();

    for (int t = 0; t < T_LEN; ++t) {
        // h A-fragment: A[m=L15][k=q*8+j]
        bf16x8 hfrag = *(const bf16x8*)(&h_lds[L15 * 40 + q * 8]);

        // convert prefetched x, issue next prefetch
        bf16x8 xfrag = (bf16x8){0,0,0,0,0,0,0,0};
        if (q == 0) {
            xfrag[0] = f2bf(xr0.x); xfrag[1] = f2bf(xr0.y);
            xfrag[2] = f2bf(xr0.z); xfrag[3] = f2bf(xr0.w);
            xfrag[4] = f2bf(xr1.x); xfrag[5] = f2bf(xr1.y);
            xfrag[6] = f2bf(xr1.z); xfrag[7] = f2bf(xr1.w);
            const int tn = (t + 1 < T_LEN) ? t + 1 : t;
            xr0 = xv[xbase + (size_t)tn * 2];
            xr1 = xv[xbase + (size_t)tn * 2 + 1];
        }

        // z' = log2e * (x W_ih^T + b + h W_hh^T): 4 MFMAs, bias as C-init
        f32x4 acc[2];
#pragma unroll
        for (int a = 0; a < 2; ++a) {
            f32x4 z = __builtin_amdgcn_mfma_f32_16x16x32_bf16(xfrag, wih[a], bias4[a], 0, 0, 0);
            z = __builtin_amdgcn_mfma_f32_16x16x32_bf16(hfrag, whh[a], z, 0, 0, 0);
            acc[a] = z;
        }

        // activate (wave-uniform branch: wave 2 = tanh, others = sigmoid) and
        // store to gate_lds[w][j=16a+L15][m=4q..4q+3]
#pragma unroll
        for (int a = 0; a < 2; ++a) {
            f32x4 v;
            if (w == 2) {
#pragma unroll
                for (int r = 0; r < 4; ++r) {
                    const float zz = acc[a][r];
                    const float e  = __builtin_amdgcn_exp2f(-(zz + zz));
                    v[r] = 2.f * __builtin_amdgcn_rcpf(1.f + e) - 1.f;  // tanh
                }
            } else {
#pragma unroll
                for (int r = 0; r < 4; ++r) {
                    const float e = __builtin_amdgcn_exp2f(-acc[a][r]);
                    v[r] = __builtin_amdgcn_rcpf(1.f + e);              // sigmoid
                }
            }
            *(f32x4*)(&gate_lds[(w * 32 + 16 * a + L15) * 20 + 4 * q]) = v;
        }
        __syncthreads();

        // c/h update: 2 elements per lane, (m=um+e, j=uj)
        {
            const float2 iv = *(const float2*)(&gate_lds[(0 * 32 + uj) * 20 + um]);
            const float2 fv = *(const float2*)(&gate_lds[(1 * 32 + uj) * 20 + um]);
            const float2 gv = *(const float2*)(&gate_lds[(2 * 32 + uj) * 20 + um]);
            const float2 ov = *(const float2*)(&gate_lds[(3 * 32 + uj) * 20 + um]);

            c0 = fmaf(fv.x, c0, iv.x * gv.x);
            c1 = fmaf(fv.y, c1, iv.y * gv.y);

            const float e0 = __builtin_amdgcn_exp2f(-c0 * (2.f * LOG2E));
            const float e1 = __builtin_amdgcn_exp2f(-c1 * (2.f * LOG2E));
            const float th0 = 2.f * __builtin_amdgcn_rcpf(1.f + e0) - 1.f;
            const float th1 = 2.f * __builtin_amdgcn_rcpf(1.f + e1) - 1.f;
            const float h0 = ov.x * th0;
            const float h1 = ov.y * th1;

            h_lds[um * 40 + uj]       = f2bf(h0);
            h_lds[(um + 1) * 40 + uj] = f2bf(h1);
        }
        __syncthreads();
    }

    // epilogue: out[b] = h_T[b,:] . W_out + b_out   (16 rows, lanes 0..15 of wave 0)
    if (tid < 16) {
        float s = b_out[0];
#pragma unroll
        for (int k = 0; k < 32; ++k) s = fmaf(bf2f(h_lds[tid * 40 + k]), W_out[k], s);
        out[row0 + tid] = s;
    }
}

extern "C" void kernel_launch(void* const* d_in, const int* in_sizes, int n_in,
                              void* d_out, int out_size, void* d_ws, size_t ws_size,
                              hipStream_t stream) {
    const float* x     = (const float*)d_in[0];
    const float* W_ih  = (const float*)d_in[1];
    const float* W_hh  = (const float*)d_in[2];
    const float* b_ih  = (const float*)d_in[3];
    const float* b_hh  = (const float*)d_in[4];
    const float* W_out = (const float*)d_in[5];
    const float* b_out = (const float*)d_in[6];
    float* out = (float*)d_out;

    const int B = in_sizes[0] / (T_LEN * 8);  // 4096
    const int tiles = B / 16;                 // 256
    lstm_kernel<<<tiles, 256, 0, stream>>>(x, W_ih, W_hh, b_ih, b_hh, W_out, b_out, out);
}

// Round 2
// 165.684 us; speedup vs baseline: 1.3224x; 1.3224x over previous
//
#include <hip/hip_runtime.h>

// LSTM: B=4096, T=256, I=8, H=32, O=1, fp32 in/out, bf16 MFMA compute.
// 256 blocks (1/CU) x 256 threads; block owns 16 batch rows; wave w owns
// hidden slice j in {8w+4p+q}. Weights sit in the MFMA *first* operand with
// permuted rows (fr -> gate=fr&3, j=8w+4p+(fr>>2)) so each lane's 4 accum
// regs are the 4 gates (i,f,g,o) at one (m,j): c/h update is fully
// in-register -- no gate LDS, no gate barrier. h exchanged via
// double-buffered LDS + ONE raw s_barrier/step with LDS-only fences
// (no vmcnt drain -> x prefetch ring depth 2 survives the barrier).
// Weights pre-scaled by log2e so sigmoid/tanh = v_exp_f32 + v_rcp_f32.

#define T_LEN 256
#define LOG2E 1.4426950408889634f

typedef __attribute__((ext_vector_type(8))) short bf16x8;
typedef __attribute__((ext_vector_type(4))) float f32x4;

static __device__ inline short f2bf(float f) {
    union { float f; unsigned u; } v; v.f = f;
    unsigned u = v.u;
    unsigned r = (u + 0x7FFFu + ((u >> 16) & 1u)) >> 16;  // RNE
    return (short)r;
}
static __device__ inline float bf2f(short s) {
    union { unsigned u; float f; } v;
    v.u = ((unsigned)(unsigned short)s) << 16;
    return v.f;
}

static __device__ inline float sig_p(float zp) {           // sigmoid, z pre-scaled by log2e
    return __builtin_amdgcn_rcpf(1.f + __builtin_amdgcn_exp2f(-zp));
}
static __device__ inline float tanh_p(float zp) {          // tanh, z pre-scaled by log2e
    return 2.f * __builtin_amdgcn_rcpf(1.f + __builtin_amdgcn_exp2f(-(zp + zp))) - 1.f;
}

__global__ __launch_bounds__(256) void lstm_kernel(
    const float* __restrict__ x, const float* __restrict__ W_ih,
    const float* __restrict__ W_hh, const float* __restrict__ b_ih,
    const float* __restrict__ b_hh, const float* __restrict__ W_out,
    const float* __restrict__ b_out, float* __restrict__ out)
{
    // h double buffer: [buf][m(0..15)][k(0..31)] bf16, row stride 40 shorts
    // (80 B, 16B-aligned b128 reads; m vs m+8 alias 2-way = free)
    __shared__ __attribute__((aligned(16))) short h_lds[2][16 * 40];

    const int tid  = threadIdx.x;
    const int w    = tid >> 6;        // wave 0..3 -> hidden slice
    const int lane = tid & 63;
    const int L    = lane & 15;       // batch row within tile / fragment row
    const int q    = lane >> 4;       // quad
    const int row0 = blockIdx.x * 16;

    // ---- one-time: weight fragments, FIRST-operand layout [row=L][k=q*8+j] ----
    // frag p row fr holds W row n = 32*(fr&3) + 8w + 4p + (fr>>2)
    bf16x8 whh[2], wih[2];
    f32x4  bias4[2];
#pragma unroll
    for (int p = 0; p < 2; ++p) {
        const int n = 32 * (L & 3) + 8 * w + 4 * p + (L >> 2);
        const float* src = W_hh + n * 32 + q * 8;
        bf16x8 fr;
#pragma unroll
        for (int j = 0; j < 8; ++j) fr[j] = f2bf(src[j] * LOG2E);
        whh[p] = fr;
        bf16x8 gr = (bf16x8){0,0,0,0,0,0,0,0};
        if (q == 0) {                              // only k=0..7 exist (I=8)
            const float* s2 = W_ih + n * 8;
#pragma unroll
            for (int j = 0; j < 8; ++j) gr[j] = f2bf(s2[j] * LOG2E);
        }
        wih[p] = gr;
        // bias in C-layout: reg r = row fr=4q+r -> n_r = 32r + 8w + 4p + q
        f32x4 bb;
#pragma unroll
        for (int r = 0; r < 4; ++r) {
            const int nr = 32 * r + 8 * w + 4 * p + q;
            bb[r] = (b_ih[nr] + b_hh[nr]) * LOG2E;
        }
        bias4[p] = bb;
    }

    // zero h(0) buffer
    for (int i = tid; i < 16 * 40; i += 256) h_lds[0][i] = 0;

    // x prefetch ring, depth 2: slot t&1 holds x(t); q==0 lanes only
    const float4* xv = (const float4*)x;
    const size_t xbase = (size_t)(row0 + L) * (T_LEN * 8 / 4);
    float4 xr0[2] = {{0,0,0,0},{0,0,0,0}}, xr1[2] = {{0,0,0,0},{0,0,0,0}};
    if (q == 0) {
        xr0[0] = xv[xbase + 0]; xr1[0] = xv[xbase + 1];
        xr0[1] = xv[xbase + 2]; xr1[1] = xv[xbase + 3];
    }

    float c0 = 0.f, c1 = 0.f;                      // c at (m=L, j=8w+4p+q)
    const int jme = 8 * w + q;                     // j for p=0 (p=1: +4)

    __syncthreads();

#pragma unroll 2
    for (int t = 0; t < T_LEN; ++t) {
        const int par = t & 1;
        // h(t) A-style fragment: [m=L][k=q*8+j]
        bf16x8 hfrag = *(const bf16x8*)(&h_lds[par][L * 40 + q * 8]);

        // consume prefetched x(t), refill slot with x(t+2)
        bf16x8 xfrag = (bf16x8){0,0,0,0,0,0,0,0};
        if (q == 0) {
            const float4 a = xr0[par], b = xr1[par];
            xfrag[0] = f2bf(a.x); xfrag[1] = f2bf(a.y);
            xfrag[2] = f2bf(a.z); xfrag[3] = f2bf(a.w);
            xfrag[4] = f2bf(b.x); xfrag[5] = f2bf(b.y);
            xfrag[6] = f2bf(b.z); xfrag[7] = f2bf(b.w);
            int tn = t + 2; if (tn >= T_LEN) tn = T_LEN - 1;
            xr0[par] = xv[xbase + (size_t)tn * 2];
            xr1[par] = xv[xbase + (size_t)tn * 2 + 1];
        }

        // z' = log2e*(x W_ih^T + b + h W_hh^T); weights are FIRST operand
        f32x4 acc[2];
#pragma unroll
        for (int p = 0; p < 2; ++p) {
            f32x4 z = __builtin_amdgcn_mfma_f32_16x16x32_bf16(wih[p], xfrag, bias4[p], 0, 0, 0);
            z = __builtin_amdgcn_mfma_f32_16x16x32_bf16(whh[p], hfrag, z, 0, 0, 0);
            acc[p] = z;
        }

        // in-register gate activation + c/h update; regs r = (i,f,g,o)
        {
            const float i0 = sig_p(acc[0][0]), f0 = sig_p(acc[0][1]);
            const float g0 = tanh_p(acc[0][2]), o0 = sig_p(acc[0][3]);
            const float i1 = sig_p(acc[1][0]), f1 = sig_p(acc[1][1]);
            const float g1 = tanh_p(acc[1][2]), o1 = sig_p(acc[1][3]);
            c0 = fmaf(f0, c0, i0 * g0);
            c1 = fmaf(f1, c1, i1 * g1);
            const float h0 = o0 * tanh_p(c0 * LOG2E);
            const float h1 = o1 * tanh_p(c1 * LOG2E);
            short* dst = &h_lds[par ^ 1][L * 40 + jme];
            dst[0] = f2bf(h0);
            dst[4] = f2bf(h1);
        }

        // LDS-only release/acquire around a raw barrier: no vmcnt drain,
        // x prefetch stays in flight across steps.
        __builtin_amdgcn_fence(__ATOMIC_RELEASE, "workgroup", "local");
        __builtin_amdgcn_s_barrier();
        __builtin_amdgcn_fence(__ATOMIC_ACQUIRE, "workgroup", "local");
    }

    // final h = h(T) lives in buf[(255+1)&1] = buf[0]
    if (tid < 16) {
        float s = b_out[0];
#pragma unroll
        for (int k = 0; k < 32; ++k) s = fmaf(bf2f(h_lds[0][tid * 40 + k]), W_out[k], s);
        out[row0 + tid] = s;
    }
}

extern "C" void kernel_launch(void* const* d_in, const int* in_sizes, int n_in,
                              void* d_out, int out_size, void* d_ws, size_t ws_size,
                              hipStream_t stream) {
    const float* x     = (const float*)d_in[0];
    const float* W_ih  = (const float*)d_in[1];
    const float* W_hh  = (const float*)d_in[2];
    const float* b_ih  = (const float*)d_in[3];
    const float* b_hh  = (const float*)d_in[4];
    const float* W_out = (const float*)d_in[5];
    const float* b_out = (const float*)d_in[6];
    float* out = (float*)d_out;

    const int B = in_sizes[0] / (T_LEN * 8);  // 4096
    const int tiles = B / 16;                 // 256
    lstm_kernel<<<tiles, 256, 0, stream>>>(x, W_ih, W_hh, b_ih, b_hh, W_out, b_out, out);
}